// Round 5
// baseline (153.225 us; speedup 1.0000x reference)
//
#include <hip/hip_runtime.h>

typedef float f32x4 __attribute__((ext_vector_type(4)));
typedef __bf16 bf16x8 __attribute__((ext_vector_type(8)));
typedef unsigned short u16;

__device__ __forceinline__ f32x4 mfma16(bf16x8 a, bf16x8 b, f32x4 c) {
  return __builtin_amdgcn_mfma_f32_16x16x32_bf16(a, b, c, 0, 0, 0);
}

__device__ __forceinline__ void gll16(const void* g, void* l) {
  __builtin_amdgcn_global_load_lds(
      (const __attribute__((address_space(1))) void*)g,
      (__attribute__((address_space(3))) void*)l, 16, 0, 0);
}

// ---------------- f32 -> bf16 convert ----------------
__global__ void cvt_kernel(const float* __restrict__ in, __bf16* __restrict__ out, int n8) {
  int idx = blockIdx.x * blockDim.x + threadIdx.x;
  int stride = gridDim.x * blockDim.x;
  for (int i = idx; i < n8; i += stride) {
    const float* p = in + (size_t)i * 8;
    f32x4 a = *(const f32x4*)p;
    f32x4 b = *(const f32x4*)(p + 4);
    bf16x8 r;
#pragma unroll
    for (int j = 0; j < 4; ++j) {
      r[j] = (__bf16)a[j];
      r[4 + j] = (__bf16)b[j];
    }
    *(bf16x8*)(out + (size_t)i * 8) = r;
  }
}

// ---------------- bf16 GEMM: C = A @ B^T + bias ----------------
// MODE 0: plain f32 output to Cout.
// MODE 1: QKV pack: Q -> qb [4096,1024]; K -> kp tiles [bh][t][s'][d] swizzled;
//         V -> vp tiles [bh][t][d][s'] swizzled. chunk(col16B) ^= (row&7).
template <int MODE>
__global__ __launch_bounds__(256, 2) void gemm_bt(
    const u16* __restrict__ A, const u16* __restrict__ B,
    const float* __restrict__ bias, float* __restrict__ Cout,
    __bf16* __restrict__ qb, __bf16* __restrict__ kp, __bf16* __restrict__ vp,
    int M, int N, int K) {
  __shared__ u16 lA[128 * 32];
  __shared__ u16 lB[128 * 32];
  const int tid = threadIdx.x;
  const int wid = tid >> 6;
  const int lane = tid & 63;
  const int lr = lane & 15;
  const int lg = lane >> 4;
  const int bm = blockIdx.x * 128;
  const int bn = blockIdx.y * 128;
  const int wm = (wid >> 1) * 64;
  const int wn = (wid & 1) * 64;

  f32x4 acc[4][4] = {};

  for (int kt = 0; kt < K; kt += 32) {
    __syncthreads();
#pragma unroll
    for (int j = 0; j < 2; ++j) {
      int beta = tid * 16 + j * 4096;
      int row = beta >> 6;
      int ce = (beta & 63) >> 1;
      gll16(A + (size_t)(bm + row) * K + kt + ce,
            (char*)lA + (wid << 10) + (j << 12));
      gll16(B + (size_t)(bn + row) * K + kt + ce,
            (char*)lB + (wid << 10) + (j << 12));
    }
    __syncthreads();
    bf16x8 af[4], bfr[4];
#pragma unroll
    for (int mt = 0; mt < 4; ++mt)
      af[mt] = *(const bf16x8*)&lA[(wm + mt * 16 + lr) * 32 + lg * 8];
#pragma unroll
    for (int nt = 0; nt < 4; ++nt)
      bfr[nt] = *(const bf16x8*)&lB[(wn + nt * 16 + lr) * 32 + lg * 8];
#pragma unroll
    for (int mt = 0; mt < 4; ++mt)
#pragma unroll
      for (int nt = 0; nt < 4; ++nt)
        acc[mt][nt] = mfma16(af[mt], bfr[nt], acc[mt][nt]);
  }

#pragma unroll
  for (int nt = 0; nt < 4; ++nt) {
    int col = bn + wn + nt * 16 + lr;
    float bv = bias[col];
#pragma unroll
    for (int mt = 0; mt < 4; ++mt) {
#pragma unroll
      for (int r = 0; r < 4; ++r) {
        int row = bm + wm + mt * 16 + lg * 4 + r;
        float val = acc[mt][nt][r] + bv;
        if (MODE == 0) {
          Cout[(size_t)row * N + col] = val;
        } else {
          __bf16 bx = (__bf16)val;
          int b = row >> 11, s = row & 2047;
          int third = col >> 10, hd = col & 1023;
          int h = hd >> 6, d = hd & 63;
          if (third == 0) {
            qb[(size_t)row * 1024 + hd] = bx;
          } else {
            int bh = b * 16 + h, t = s >> 6, sr = s & 63;
            size_t tb = ((size_t)(bh * 32 + t)) * 4096;
            if (third == 1)
              kp[tb + sr * 64 + (((d >> 3) ^ (sr & 7)) << 3) + (d & 7)] = bx;
            else
              vp[tb + d * 64 + ((((sr >> 3)) ^ (d & 7)) << 3) + (sr & 7)] = bx;
          }
        }
      }
    }
  }
}

// ---------------- fused causal+ALiBi flash attention ----------------
// Uniform-work pairing: block handles qtiles (63-pr) then (pr), QBLK=32,
// exactly 33 kv-tiles per block. 2 independent waves/block (no barriers).
// K/V read DIRECTLY from packed L2-resident tiles (no LDS staging).
// XCD swizzle: 4 bh per XCD (K/V set = 2 MB, L2-fit).
// Defer-max online softmax (THR=8 in log2 units, m init 0).
__global__ __launch_bounds__(128, 4) void attn_kernel(
    const __bf16* __restrict__ qb, const __bf16* __restrict__ kp,
    const __bf16* __restrict__ vp, __bf16* __restrict__ aout) {
  __shared__ __bf16 p_lds[2][16][72];
  const int tid = threadIdx.x;
  const int wid = tid >> 6;
  const int lane = tid & 63;
  const int lr = lane & 15;
  const int lg = lane >> 4;

  const int lid = blockIdx.y * 32 + blockIdx.x;
  const int xcd = lid & 7;
  const int slot = lid >> 3;           // 0..127
  const int bh = xcd * 4 + (slot >> 5);
  const int pr = slot & 31;
  const int b = bh >> 4, h = bh & 15;

  const float LOG2E = 1.4426950408889634f;
  const float c1 = 0.125f * LOG2E;
  const float c2 = exp2f(-(float)(h + 1) * 0.5f) * LOG2E;

  bf16x8 ones;
#pragma unroll
  for (int j = 0; j < 8; ++j) ones[j] = (__bf16)1.0f;

  const u16* ktiles = (const u16*)(kp + (size_t)bh * 32 * 4096);
  const u16* vtiles = (const u16*)(vp + (size_t)bh * 32 * 4096);

  const int sx0 = (lg ^ (lr & 7)) << 3;        // swizzled chunk, frag0
  const int sx1 = ((lg + 4) ^ (lr & 7)) << 3;  // swizzled chunk, frag1

  for (int ph = 0; ph < 2; ++ph) {
    const int q32 = ph ? pr : 63 - pr;
    const int qbase = q32 * 32;
    const int ntl = (q32 >> 1) + 1;  // kv tiles needed
    const int qr0 = qbase + wid * 16;

    const __bf16* qrow = qb + (size_t)(b * 2048 + qr0 + lr) * 1024 + h * 64;
    bf16x8 qf0 = *(const bf16x8*)(qrow + lg * 8);
    bf16x8 qf1 = *(const bf16x8*)(qrow + 32 + lg * 8);

    float m[4], l[4], cq[4];
    f32x4 o[4];
#pragma unroll
    for (int r = 0; r < 4; ++r) {
      m[r] = 0.f;  // defer-max: safe start, violations handled below
      l[r] = 0.f;
      cq[r] = c2 * (float)(qr0 + lg * 4 + r);
    }
#pragma unroll
    for (int dt = 0; dt < 4; ++dt) o[dt] = (f32x4){0.f, 0.f, 0.f, 0.f};

    for (int t = 0; t < ntl; ++t) {
      const u16* kbuf = ktiles + (size_t)t * 4096;
      const u16* vbuf = vtiles + (size_t)t * 4096;
      const int kv = t * 64;
      const bool last = (t == ntl - 1);

      // ---- QK^T (K fragments direct from L2) ----
      f32x4 s[4];
#pragma unroll
      for (int nt = 0; nt < 4; ++nt) {
        int rb = (nt * 16 + lr) * 64;
        bf16x8 k0 = *(const bf16x8*)&kbuf[rb + sx0];
        bf16x8 k1 = *(const bf16x8*)&kbuf[rb + sx1];
        f32x4 tt = (f32x4){0.f, 0.f, 0.f, 0.f};
        tt = mfma16(qf0, k0, tt);
        tt = mfma16(qf1, k1, tt);
        s[nt] = tt;
      }

      // ---- logits (log2 domain) ----
#pragma unroll
      for (int nt = 0; nt < 4; ++nt) {
        float bnt = c2 * (float)(kv + nt * 16 + lr);
#pragma unroll
        for (int r = 0; r < 4; ++r)
          s[nt][r] = __builtin_fmaf(s[nt][r], c1, bnt - cq[r]);
      }
      if (last) {  // diagonal tile: causal mask
#pragma unroll
        for (int nt = 0; nt < 4; ++nt) {
          float kf = (float)(kv + nt * 16 + lr);
#pragma unroll
          for (int r = 0; r < 4; ++r) {
            float qi = (float)(qr0 + lg * 4 + r);
            if (kf > qi) s[nt][r] = -1e30f;
          }
        }
      }

      // ---- defer-max check (no cross-lane in common path) ----
      float pm[4];
#pragma unroll
      for (int r = 0; r < 4; ++r)
        pm[r] = fmaxf(fmaxf(s[0][r], s[1][r]), fmaxf(s[2][r], s[3][r]));
      bool ok = (pm[0] <= m[0] + 8.f) && (pm[1] <= m[1] + 8.f) &&
                (pm[2] <= m[2] + 8.f) && (pm[3] <= m[3] + 8.f);
      if (!__all(ok)) {  // rare: full reduce + rescale
#pragma unroll
        for (int r = 0; r < 4; ++r)
#pragma unroll
          for (int d = 1; d < 16; d <<= 1)
            pm[r] = fmaxf(pm[r], __shfl_xor(pm[r], d));
#pragma unroll
        for (int r = 0; r < 4; ++r) {
          float mn = fmaxf(m[r], pm[r]);
          float fac = __builtin_amdgcn_exp2f(m[r] - mn);
          m[r] = mn;
          l[r] *= fac;
#pragma unroll
          for (int dt = 0; dt < 4; ++dt) o[dt][r] *= fac;
        }
      }

      // ---- P = exp2(s - m), store to per-wave LDS ----
#pragma unroll
      for (int nt = 0; nt < 4; ++nt)
#pragma unroll
        for (int r = 0; r < 4; ++r) {
          float e = __builtin_amdgcn_exp2f(s[nt][r] - m[r]);
          p_lds[wid][lg * 4 + r][nt * 16 + lr] = (__bf16)e;
        }

      // wave-private LDS: compiler orders via lgkmcnt, no barrier needed
      bf16x8 pa0 = *(const bf16x8*)&p_lds[wid][lr][lg * 8];
      bf16x8 pa1 = *(const bf16x8*)&p_lds[wid][lr][32 + lg * 8];

      // ---- row-sum via ones-MFMA ----
      {
        f32x4 tt = (f32x4){0.f, 0.f, 0.f, 0.f};
        tt = mfma16(pa0, ones, tt);
        tt = mfma16(pa1, ones, tt);
#pragma unroll
        for (int r = 0; r < 4; ++r) l[r] += tt[r];
      }

      // ---- PV (V fragments direct from L2) ----
#pragma unroll
      for (int dt = 0; dt < 4; ++dt) {
        int rb = (dt * 16 + lr) * 64;
        bf16x8 v0 = *(const bf16x8*)&vbuf[rb + sx0];
        bf16x8 v1 = *(const bf16x8*)&vbuf[rb + sx1];
        o[dt] = mfma16(pa0, v0, o[dt]);
        o[dt] = mfma16(pa1, v1, o[dt]);
      }
    }

    // ---- epilogue for this qtile ----
#pragma unroll
    for (int dt = 0; dt < 4; ++dt)
#pragma unroll
      for (int r = 0; r < 4; ++r) {
        float val = o[dt][r] / l[r];
        aout[(size_t)(b * 2048 + qr0 + lg * 4 + r) * 1024 + h * 64 + dt * 16 + lr] =
            (__bf16)val;
      }
  }
}

extern "C" void kernel_launch(void* const* d_in, const int* in_sizes, int n_in,
                              void* d_out, int out_size, void* d_ws, size_t ws_size,
                              hipStream_t stream) {
  (void)in_sizes; (void)n_in; (void)out_size; (void)ws_size;
  const float* x = (const float*)d_in[0];
  const float* Wp = (const float*)d_in[1];
  const float* bp = (const float*)d_in[2];
  const float* Wo = (const float*)d_in[3];
  const float* bo = (const float*)d_in[4];
  float* out = (float*)d_out;

  char* ws = (char*)d_ws;
  u16* xb  = (u16*)(ws);                        // 8 MB  x bf16 [4096,1024]
  u16* wpb = (u16*)(ws + (size_t)(8u << 20));   // 6 MB  W_packed bf16
  u16* wob = (u16*)(ws + (size_t)(14u << 20));  // 2 MB  W_out bf16
  u16* qbp = (u16*)(ws + (size_t)(16u << 20));  // 8 MB  Q [4096,1024]
  u16* kpp = (u16*)(ws + (size_t)(24u << 20));  // 8 MB  K packed tiles
  u16* vpp = (u16*)(ws + (size_t)(32u << 20));  // 8 MB  V packed tiles
  u16* ab  = xb;  // attention output reuses x_bf16 space

  cvt_kernel<<<2048, 256, 0, stream>>>(x, (__bf16*)xb, 4096 * 1024 / 8);
  cvt_kernel<<<1536, 256, 0, stream>>>(Wp, (__bf16*)wpb, 3072 * 1024 / 8);
  cvt_kernel<<<512, 256, 0, stream>>>(Wo, (__bf16*)wob, 1024 * 1024 / 8);
  gemm_bt<1><<<dim3(32, 24), 256, 0, stream>>>(
      xb, wpb, bp, nullptr, (__bf16*)qbp, (__bf16*)kpp, (__bf16*)vpp,
      4096, 3072, 1024);
  attn_kernel<<<dim3(32, 32), 128, 0, stream>>>(
      (const __bf16*)qbp, (const __bf16*)kpp, (const __bf16*)vpp, (__bf16*)ab);
  gemm_bt<0><<<dim3(32, 8), 256, 0, stream>>>(
      ab, wob, bo, out, nullptr, nullptr, nullptr, 4096, 1024, 1024);
}

// Round 6
// 116.265 us; speedup vs baseline: 1.3179x; 1.3179x over previous
//
#include <hip/hip_runtime.h>

typedef float f32x4 __attribute__((ext_vector_type(4)));
typedef __bf16 bf16x8 __attribute__((ext_vector_type(8)));
typedef unsigned short u16;

__device__ __forceinline__ f32x4 mfma16(bf16x8 a, bf16x8 b, f32x4 c) {
  return __builtin_amdgcn_mfma_f32_16x16x32_bf16(a, b, c, 0, 0, 0);
}

__device__ __forceinline__ void gll16(const void* g, void* l) {
  __builtin_amdgcn_global_load_lds(
      (const __attribute__((address_space(1))) void*)g,
      (__attribute__((address_space(3))) void*)l, 16, 0, 0);
}

// ---------------- f32 -> bf16 convert ----------------
__global__ void cvt_kernel(const float* __restrict__ in, __bf16* __restrict__ out, int n8) {
  int idx = blockIdx.x * blockDim.x + threadIdx.x;
  int stride = gridDim.x * blockDim.x;
  for (int i = idx; i < n8; i += stride) {
    const float* p = in + (size_t)i * 8;
    f32x4 a = *(const f32x4*)p;
    f32x4 b = *(const f32x4*)(p + 4);
    bf16x8 r;
#pragma unroll
    for (int j = 0; j < 4; ++j) {
      r[j] = (__bf16)a[j];
      r[4 + j] = (__bf16)b[j];
    }
    *(bf16x8*)(out + (size_t)i * 8) = r;
  }
}

// ---------------- bf16 GEMM: C = A @ B^T + bias ----------------
// MODE 0: plain f32 output to Cout.
// MODE 1: QKV pack: Q -> qb [4096,1024] row-major;
//   K -> kp, V -> vp in MFMA-FRAGMENT-LINEAR tile order:
//   tile = 64 kv x 64 d per (bh, t). Within tile: [frag(0..3)][reg(0..1)]
//   [lane(0..63)][8 elems] so each fragment load is a contiguous 1 KB.
//   K element (sr, d): frag=sr>>4, reg=d>>5, lane=((d>>3)&3)*16+(sr&15), e=d&7
//   V element (sr, d): frag=d>>4, reg=sr>>5, lane=((sr>>3)&3)*16+(d&15), e=sr&7
template <int MODE>
__global__ __launch_bounds__(256, 2) void gemm_bt(
    const u16* __restrict__ A, const u16* __restrict__ B,
    const float* __restrict__ bias, float* __restrict__ Cout,
    __bf16* __restrict__ qb, __bf16* __restrict__ kp, __bf16* __restrict__ vp,
    int M, int N, int K) {
  __shared__ u16 lA[128 * 32];
  __shared__ u16 lB[128 * 32];
  const int tid = threadIdx.x;
  const int wid = tid >> 6;
  const int lane = tid & 63;
  const int lr = lane & 15;
  const int lg = lane >> 4;
  const int bm = blockIdx.x * 128;
  const int bn = blockIdx.y * 128;
  const int wm = (wid >> 1) * 64;
  const int wn = (wid & 1) * 64;

  f32x4 acc[4][4] = {};

  for (int kt = 0; kt < K; kt += 32) {
    __syncthreads();
#pragma unroll
    for (int j = 0; j < 2; ++j) {
      int beta = tid * 16 + j * 4096;
      int row = beta >> 6;
      int ce = (beta & 63) >> 1;
      gll16(A + (size_t)(bm + row) * K + kt + ce,
            (char*)lA + (wid << 10) + (j << 12));
      gll16(B + (size_t)(bn + row) * K + kt + ce,
            (char*)lB + (wid << 10) + (j << 12));
    }
    __syncthreads();
    bf16x8 af[4], bfr[4];
#pragma unroll
    for (int mt = 0; mt < 4; ++mt)
      af[mt] = *(const bf16x8*)&lA[(wm + mt * 16 + lr) * 32 + lg * 8];
#pragma unroll
    for (int nt = 0; nt < 4; ++nt)
      bfr[nt] = *(const bf16x8*)&lB[(wn + nt * 16 + lr) * 32 + lg * 8];
#pragma unroll
    for (int mt = 0; mt < 4; ++mt)
#pragma unroll
      for (int nt = 0; nt < 4; ++nt)
        acc[mt][nt] = mfma16(af[mt], bfr[nt], acc[mt][nt]);
  }

#pragma unroll
  for (int nt = 0; nt < 4; ++nt) {
    int col = bn + wn + nt * 16 + lr;
    float bv = bias[col];
#pragma unroll
    for (int mt = 0; mt < 4; ++mt) {
#pragma unroll
      for (int r = 0; r < 4; ++r) {
        int row = bm + wm + mt * 16 + lg * 4 + r;
        float val = acc[mt][nt][r] + bv;
        if (MODE == 0) {
          Cout[(size_t)row * N + col] = val;
        } else {
          __bf16 bx = (__bf16)val;
          int b = row >> 11, s = row & 2047;
          int third = col >> 10, hd = col & 1023;
          int h = hd >> 6, d = hd & 63;
          if (third == 0) {
            qb[(size_t)row * 1024 + hd] = bx;
          } else {
            int bh = b * 16 + h, t = s >> 6, sr = s & 63;
            size_t tb = ((size_t)(bh * 32 + t)) * 4096;
            if (third == 1)
              kp[tb + (sr >> 4) * 1024 + (d >> 5) * 512 + ((d >> 3) & 3) * 128 +
                 (sr & 15) * 8 + (d & 7)] = bx;
            else
              vp[tb + (d >> 4) * 1024 + (sr >> 5) * 512 + ((sr >> 3) & 3) * 128 +
                 (d & 15) * 8 + (sr & 7)] = bx;
          }
        }
      }
    }
  }
}

// ---------------- fused causal+ALiBi flash attention ----------------
// 4096 independent 1-wave blocks: one 16-row qtile (a16 = 0..127 per bh) each,
// launched big-first for dynamic load balance. No barriers, no KV LDS.
// K/V fragments read as contiguous 1 KB loads from fragment-linear tiles
// (L2-resident: 4 bh per XCD = 2 MB). Defer-max online softmax (THR=8 log2).
__global__ __launch_bounds__(64, 4) void attn_kernel(
    const __bf16* __restrict__ qb, const __bf16* __restrict__ kp,
    const __bf16* __restrict__ vp, __bf16* __restrict__ aout) {
  __shared__ __bf16 p_lds[16][72];
  const int lane = threadIdx.x & 63;
  const int lr = lane & 15;
  const int lg = lane >> 4;

  const int lid = blockIdx.x;
  const int xcd = lid & 7;
  const int rest = lid >> 3;            // 0..511
  const int bh = xcd * 4 + (rest & 3);  // 4 bh per XCD
  const int a16 = 127 - (rest >> 2);    // qtile, descending (big blocks first)
  const int b = bh >> 4, h = bh & 15;
  const int qr0 = a16 * 16;
  const int ntl = (a16 >> 2) + 1;  // kv tiles needed

  const float LOG2E = 1.4426950408889634f;
  const float c1 = 0.125f * LOG2E;
  const float c2 = exp2f(-(float)(h + 1) * 0.5f) * LOG2E;

  bf16x8 ones;
#pragma unroll
  for (int j = 0; j < 8; ++j) ones[j] = (__bf16)1.0f;

  const u16* ktiles = (const u16*)kp + (size_t)bh * 32 * 4096;
  const u16* vtiles = (const u16*)vp + (size_t)bh * 32 * 4096;

  const __bf16* qrow = qb + (size_t)(b * 2048 + qr0 + lr) * 1024 + h * 64;
  bf16x8 qf0 = *(const bf16x8*)(qrow + lg * 8);
  bf16x8 qf1 = *(const bf16x8*)(qrow + 32 + lg * 8);

  float m[4], l[4], cq[4];
  f32x4 o[4];
#pragma unroll
  for (int r = 0; r < 4; ++r) {
    m[r] = 0.f;  // defer-max: safe start, violations handled below
    l[r] = 0.f;
    cq[r] = c2 * (float)(qr0 + lg * 4 + r);
  }
#pragma unroll
  for (int dt = 0; dt < 4; ++dt) o[dt] = (f32x4){0.f, 0.f, 0.f, 0.f};

  for (int t = 0; t < ntl; ++t) {
    const u16* kb = ktiles + (size_t)t * 4096;
    const u16* vb = vtiles + (size_t)t * 4096;
    const int kv = t * 64;
    const bool last = (t == ntl - 1);

    // ---- issue all K then V fragment loads (contiguous 1 KB each);
    //      QK waits only on K (counted vmcnt), V stays in flight ----
    bf16x8 ka[8], va[8];
#pragma unroll
    for (int j = 0; j < 8; ++j)
      ka[j] = *(const bf16x8*)(kb + j * 512 + lane * 8);
#pragma unroll
    for (int j = 0; j < 8; ++j)
      va[j] = *(const bf16x8*)(vb + j * 512 + lane * 8);

    // ---- QK^T ----
    f32x4 s[4];
#pragma unroll
    for (int nt = 0; nt < 4; ++nt) {
      f32x4 tt = (f32x4){0.f, 0.f, 0.f, 0.f};
      tt = mfma16(qf0, ka[nt * 2], tt);
      tt = mfma16(qf1, ka[nt * 2 + 1], tt);
      s[nt] = tt;
    }

    // ---- logits (log2 domain) ----
#pragma unroll
    for (int nt = 0; nt < 4; ++nt) {
      float bnt = c2 * (float)(kv + nt * 16 + lr);
#pragma unroll
      for (int r = 0; r < 4; ++r)
        s[nt][r] = __builtin_fmaf(s[nt][r], c1, bnt - cq[r]);
    }
    if (last) {  // diagonal tile: causal mask
#pragma unroll
      for (int nt = 0; nt < 4; ++nt) {
        float kf = (float)(kv + nt * 16 + lr);
#pragma unroll
        for (int r = 0; r < 4; ++r) {
          float qi = (float)(qr0 + lg * 4 + r);
          if (kf > qi) s[nt][r] = -1e30f;
        }
      }
    }

    // ---- defer-max check (no cross-lane in common path) ----
    float pm[4];
#pragma unroll
    for (int r = 0; r < 4; ++r)
      pm[r] = fmaxf(fmaxf(s[0][r], s[1][r]), fmaxf(s[2][r], s[3][r]));
    bool ok = (pm[0] <= m[0] + 8.f) && (pm[1] <= m[1] + 8.f) &&
              (pm[2] <= m[2] + 8.f) && (pm[3] <= m[3] + 8.f);
    if (!__all(ok)) {  // rare: full reduce + rescale
#pragma unroll
      for (int r = 0; r < 4; ++r)
#pragma unroll
        for (int d = 1; d < 16; d <<= 1)
          pm[r] = fmaxf(pm[r], __shfl_xor(pm[r], d));
#pragma unroll
      for (int r = 0; r < 4; ++r) {
        float mn = fmaxf(m[r], pm[r]);
        float fac = __builtin_amdgcn_exp2f(m[r] - mn);
        m[r] = mn;
        l[r] *= fac;
#pragma unroll
        for (int dt = 0; dt < 4; ++dt) o[dt][r] *= fac;
      }
    }

    // ---- P = exp2(s - m), store to wave-private LDS ----
#pragma unroll
    for (int nt = 0; nt < 4; ++nt)
#pragma unroll
      for (int r = 0; r < 4; ++r) {
        float e = __builtin_amdgcn_exp2f(s[nt][r] - m[r]);
        p_lds[lg * 4 + r][nt * 16 + lr] = (__bf16)e;
      }

    // wave-private LDS: compiler orders via lgkmcnt, no barrier needed
    bf16x8 pa0 = *(const bf16x8*)&p_lds[lr][lg * 8];
    bf16x8 pa1 = *(const bf16x8*)&p_lds[lr][32 + lg * 8];

    // ---- row-sum via ones-MFMA ----
    {
      f32x4 tt = (f32x4){0.f, 0.f, 0.f, 0.f};
      tt = mfma16(pa0, ones, tt);
      tt = mfma16(pa1, ones, tt);
#pragma unroll
      for (int r = 0; r < 4; ++r) l[r] += tt[r];
    }

    // ---- PV ----
#pragma unroll
    for (int dt = 0; dt < 4; ++dt) {
      o[dt] = mfma16(pa0, va[dt * 2], o[dt]);
      o[dt] = mfma16(pa1, va[dt * 2 + 1], o[dt]);
    }
  }

  // ---- epilogue ----
#pragma unroll
  for (int dt = 0; dt < 4; ++dt)
#pragma unroll
    for (int r = 0; r < 4; ++r) {
      float val = o[dt][r] / l[r];
      aout[(size_t)(b * 2048 + qr0 + lg * 4 + r) * 1024 + h * 64 + dt * 16 + lr] =
          (__bf16)val;
    }
}

extern "C" void kernel_launch(void* const* d_in, const int* in_sizes, int n_in,
                              void* d_out, int out_size, void* d_ws, size_t ws_size,
                              hipStream_t stream) {
  (void)in_sizes; (void)n_in; (void)out_size; (void)ws_size;
  const float* x = (const float*)d_in[0];
  const float* Wp = (const float*)d_in[1];
  const float* bp = (const float*)d_in[2];
  const float* Wo = (const float*)d_in[3];
  const float* bo = (const float*)d_in[4];
  float* out = (float*)d_out;

  char* ws = (char*)d_ws;
  u16* xb  = (u16*)(ws);                        // 8 MB  x bf16 [4096,1024]
  u16* wpb = (u16*)(ws + (size_t)(8u << 20));   // 6 MB  W_packed bf16
  u16* wob = (u16*)(ws + (size_t)(14u << 20));  // 2 MB  W_out bf16
  u16* qbp = (u16*)(ws + (size_t)(16u << 20));  // 8 MB  Q [4096,1024]
  u16* kpp = (u16*)(ws + (size_t)(24u << 20));  // 8 MB  K fragment tiles
  u16* vpp = (u16*)(ws + (size_t)(32u << 20));  // 8 MB  V fragment tiles
  u16* ab  = xb;  // attention output reuses x_bf16 space

  cvt_kernel<<<2048, 256, 0, stream>>>(x, (__bf16*)xb, 4096 * 1024 / 8);
  cvt_kernel<<<1536, 256, 0, stream>>>(Wp, (__bf16*)wpb, 3072 * 1024 / 8);
  cvt_kernel<<<512, 256, 0, stream>>>(Wo, (__bf16*)wob, 1024 * 1024 / 8);
  gemm_bt<1><<<dim3(32, 24), 256, 0, stream>>>(
      xb, wpb, bp, nullptr, (__bf16*)qbp, (__bf16*)kpp, (__bf16*)vpp,
      4096, 3072, 1024);
  attn_kernel<<<4096, 64, 0, stream>>>(
      (const __bf16*)qbp, (const __bf16*)kpp, (const __bf16*)vpp, (__bf16*)ab);
  gemm_bt<0><<<dim3(32, 8), 256, 0, stream>>>(
      ab, wob, bo, out, nullptr, nullptr, nullptr, 4096, 1024, 1024);
}